// Round 13
// baseline (81.563 us; speedup 1.0000x reference)
//
#include <hip/hip_runtime.h>
#include <hip/hip_bf16.h>
#include <stdint.h>

typedef __bf16 bf16_t;
typedef __bf16 bf16x4 __attribute__((ext_vector_type(4)));
typedef __bf16 bf16x8 __attribute__((ext_vector_type(8)));
typedef float  f32x4  __attribute__((ext_vector_type(4)));

#define WAITVM(N) asm volatile("s_waitcnt vmcnt(" #N ")" ::: "memory")

// ---- workspace layout (bytes) ----
static constexpr size_t WT_OFF = 0;                    // Wt bf16 [384][1024] = 768 KB
static constexpr size_t Q_OFF  = (size_t)1 << 20;      // q bf16 (pre-scaled 1/32) 4 MB
static constexpr size_t K_OFF  = Q_OFF + ((size_t)4 << 20);
static constexpr size_t VT_OFF = K_OFF + ((size_t)4 << 20);  // vT bf16 [8][128][2048] = 4 MB

__device__ __forceinline__ void g2lds16(const void* g, void* l) {
  __builtin_amdgcn_global_load_lds(
      (__attribute__((address_space(1))) void*)(g),
      (__attribute__((address_space(3))) void*)(l), 16, 0, 0);
}

// ---------------- W transpose: W[1024][128] fp32 -> Wt[384][1024] bf16 ----------------
__global__ __launch_bounds__(256) void wt_kernel(const float* __restrict__ Wq,
                                                 const float* __restrict__ Wk,
                                                 const float* __restrict__ Wv,
                                                 bf16_t* __restrict__ wt) {
  __shared__ float tile[64][129];
  int wi = blockIdx.x >> 4;
  int ct = blockIdx.x & 15;
  const float* W = (wi == 0) ? Wq : ((wi == 1) ? Wk : Wv);
  int c0 = ct * 64;
  int tid = threadIdx.x;
  for (int i = 0; i < 32; ++i) {
    int idx = i * 256 + tid;
    int c = idx >> 7, n = idx & 127;
    tile[c][n] = W[(size_t)(c0 + c) * 128 + n];
  }
  __syncthreads();
  for (int i = 0; i < 32; ++i) {
    int idx = i * 256 + tid;
    int n = idx >> 6, c = idx & 63;
    wt[(size_t)(wi * 128 + n) * 1024 + c0 + c] = (bf16_t)tile[c][n];
  }
}

// ---------------- fused QKV projection v9b: bf16 reg-stage, n64 slices --------------
// Grid 1536 = 6 slices(n64) x 256 t-tiles(64), XCD-chunked (192/XCD). Block 128 thr
// = 2 waves (n32 halves). Single 8KB bf16 x-tile in LDS, XOR-swizzled, reg-staged
// with one fp32->bf16 conversion per element. Per thread/step: 4 wf + 8 xr loads,
// 8 ds_write_b64, 8 ds_read_b128, 16 MFMA.
__global__ __launch_bounds__(128) void proj_kernel(const float* __restrict__ x,
                                                   const bf16_t* __restrict__ wt,
                                                   bf16_t* __restrict__ q,
                                                   bf16_t* __restrict__ k,
                                                   bf16_t* __restrict__ vT) {
  __shared__ __align__(16) char Blds[8192];  // x tile [64 t][64 k] bf16, swizzled

  int wgid = (blockIdx.x & 7) * 192 + (blockIdx.x >> 3);
  int t_tile = wgid / 6;
  int sl = wgid % 6;             // slice: qkv = sl>>1 (0=Q,1=K,2=V), nh = sl&1
  int qkv = sl >> 1, nh = sl & 1;
  int n0 = qkv * 128 + nh * 64;
  int t0 = t_tile * 64;

  int tid = threadIdx.x;
  int lane = tid & 63;
  int wave = tid >> 6;           // n32-half within the n64 slice
  int lq = lane & 15, grp = lane >> 4;

  const char* xb = (const char*)x;   // global row stride 4096 B

  f32x4 acc[2][4];
#pragma unroll
  for (int a = 0; a < 2; ++a)
#pragma unroll
    for (int s = 0; s < 4; ++s) acc[a][s] = (f32x4){0.f, 0.f, 0.f, 0.f};

  const bf16_t* wbase = wt + (size_t)(n0 + wave * 32 + lq) * 1024 + grp * 8;

  // load x(ks) fp32 tile (16KB) into regs: 8 x float4/thread, 2KB/instr coalesced
  auto loadX = [&](float4* xr, int k0) {
#pragma unroll
    for (int i = 0; i < 8; ++i) {
      int foff = i * 2048 + tid * 16;      // byte offset in 16KB fp32 tile
      int row = foff >> 8;                 // 256B per row (64 floats)
      xr[i] = *(const float4*)(xb + (size_t)(t0 + row) * 4096 + (size_t)k0 * 4
                               + (foff & 255));
    }
  };
  // cvt + swizzled bf16 write: boff = foff/2; 16B-chunk ^= row&7
  auto stage = [&](const float4* xr) {
#pragma unroll
    for (int i = 0; i < 8; ++i) {
      int boff = i * 1024 + tid * 8;       // byte offset in 8KB bf16 tile
      int row = boff >> 7;                 // 128B per row
      int sw = (row << 7) | ((((boff >> 4) & 7) ^ (row & 7)) << 4) | (boff & 15);
      bf16x4 wv;
      wv[0] = (bf16_t)xr[i].x; wv[1] = (bf16_t)xr[i].y;
      wv[2] = (bf16_t)xr[i].z; wv[3] = (bf16_t)xr[i].w;
      *(bf16x4*)(&Blds[sw]) = wv;
    }
  };

  float4 xr[8];
  loadX(xr, 0);

#pragma unroll 1
  for (int ks = 0; ks < 16; ++ks) {
    int k0 = ks * 64;

    // wf(ks): 4 loads (consumed by MFMA below; compiler inserts the vm wait there)
    bf16x8 wf[2][2];
#pragma unroll
    for (int kh = 0; kh < 2; ++kh)
#pragma unroll
      for (int a = 0; a < 2; ++a)
        wf[a][kh] = *(const bf16x8*)(wbase + (size_t)(a * 16) * 1024 + k0 + kh * 32);

    WAITVM(4);                       // xr(ks) landed; wf(ks) in flight
    __builtin_amdgcn_sched_barrier(0);
    stage(xr);
    if (ks < 15) loadX(xr, (ks + 1) * 64);   // queue: [wf:4, xr(ks+1):8]
    asm volatile("s_waitcnt lgkmcnt(0)" ::: "memory");   // ds_writes visible
    __builtin_amdgcn_s_barrier();
    __builtin_amdgcn_sched_barrier(0);

    // frag reads (swizzled) + 16 MFMA
    bf16x8 xf[4][2];
#pragma unroll
    for (int sub = 0; sub < 4; ++sub) {
      int row = sub * 16 + lq;
#pragma unroll
      for (int kh = 0; kh < 2; ++kh) {
        int sw = (row << 7) | ((((kh << 2) | grp) ^ (row & 7)) << 4);
        xf[sub][kh] = *(const bf16x8*)(&Blds[sw]);
      }
    }
#pragma unroll
    for (int kh = 0; kh < 2; ++kh)
#pragma unroll
      for (int a = 0; a < 2; ++a)
#pragma unroll
        for (int sub = 0; sub < 4; ++sub)
          acc[a][sub] = __builtin_amdgcn_mfma_f32_16x16x32_bf16(wf[a][kh], xf[sub][kh],
                                                                acc[a][sub], 0, 0, 0);
    __builtin_amdgcn_s_barrier();    // all reads done -> buffer reusable
  }

  if (qkv < 2) {   // Q (pre-scaled 1/32, exact in bf16) or K, row-major [t][128]
    bf16_t* dst = (qkv == 0) ? q : k;
    float qs = (qkv == 0) ? 0.03125f : 1.0f;
#pragma unroll
    for (int a = 0; a < 2; ++a)
#pragma unroll
      for (int sub = 0; sub < 4; ++sub) {
        bf16x4 o;
        o[0] = (bf16_t)(acc[a][sub][0] * qs); o[1] = (bf16_t)(acc[a][sub][1] * qs);
        o[2] = (bf16_t)(acc[a][sub][2] * qs); o[3] = (bf16_t)(acc[a][sub][3] * qs);
        *(bf16x4*)(dst + (size_t)(t0 + sub * 16 + lq) * 128
                   + nh * 64 + wave * 32 + a * 16 + grp * 4) = o;
      }
  } else {         // V transposed: vT[b][d][t]
    int b = t0 >> 11;
#pragma unroll
    for (int a = 0; a < 2; ++a)
#pragma unroll
      for (int sub = 0; sub < 4; ++sub) {
        int tt = (t0 + sub * 16 + lq) & 2047;
#pragma unroll
        for (int r = 0; r < 4; ++r) {
          int d = nh * 64 + wave * 32 + a * 16 + grp * 4 + r;
          vT[(size_t)b * 128 * 2048 + (size_t)d * 2048 + tt] = (bf16_t)acc[a][sub][r];
        }
      }
  }
}

// ---------------- flash attention v11 (unchanged: measured ~30us) -------------------
__global__ __launch_bounds__(512) void attn_kernel(const bf16_t* __restrict__ q,
                                                   const bf16_t* __restrict__ k,
                                                   const bf16_t* __restrict__ vT,
                                                   float* __restrict__ out) {
  __shared__ __align__(16) char lds[81920];

  int tid = threadIdx.x;
  int lane = tid & 63;
  int w = tid >> 6;                  // kv-split index 0..7
  int lq = lane & 15, grp = lane >> 4;
  int b = blockIdx.x & 7;            // XCD-pinned batch
  int qt = 63 - (blockIdx.x >> 3);   // heavy first; 32 q-rows
  int tq0 = qt * 32 + lq;            // qh=0 row; qh=1 row = tq0+16

  bf16x8 qf[4][2];
#pragma unroll
  for (int qh = 0; qh < 2; ++qh) {
    const bf16_t* qrow = q + ((size_t)b * 2048 + tq0 + qh * 16) * 128 + grp * 8;
#pragma unroll
    for (int ks = 0; ks < 4; ++ks) qf[ks][qh] = *(const bf16x8*)(qrow + ks * 32);
  }

  float mrun[2] = {-__builtin_inff(), -__builtin_inff()};
  float lsum[2] = {0.f, 0.f};
  f32x4 accO[8][2];
#pragma unroll
  for (int i = 0; i < 8; ++i)
#pragma unroll
    for (int qh = 0; qh < 2; ++qh) accO[i][qh] = (f32x4){0.f, 0.f, 0.f, 0.f};

  const char* kbase = (const char*)(k + (size_t)b * 2048 * 128);
  const bf16_t* vb = vT + (size_t)b * 128 * 2048;

  auto stageK = [&](int kv0) {
#pragma unroll
    for (int i = 0; i < 8; ++i) {
      int off = i * 1024 + lane * 16;
      int row = off >> 8;
      int c = (off >> 4) & 15;
      const char* src = kbase + (size_t)(kv0 + row) * 256 + ((c ^ (row & 7)) << 4);
      g2lds16(src, &lds[w * 8192 + off]);
    }
  };

  bf16x8 vf[8];
  auto loadV = [&](int kv0) {
#pragma unroll
    for (int mf = 0; mf < 8; ++mf)
      vf[mf] = *(const bf16x8*)(vb + (size_t)(mf * 16 + lq) * 2048 + kv0 + grp * 8);
  };

  int nt = qt + 1;
  int cnt = (nt - w + 7) >> 3;

  if (cnt > 0) { stageK(w * 32); loadV(w * 32); }

#pragma unroll 1
  for (int i = 0; i < cnt; ++i) {
    int kv0 = (w + 8 * i) * 32;
    bool pre = (i + 1 < cnt);

    WAITVM(8);
    __builtin_amdgcn_sched_barrier(0);

    f32x4 s[2][2];
#pragma unroll
    for (int mf = 0; mf < 2; ++mf)
#pragma unroll
      for (int qh = 0; qh < 2; ++qh) s[mf][qh] = (f32x4){0.f, 0.f, 0.f, 0.f};
#pragma unroll
    for (int ks = 0; ks < 4; ++ks)
#pragma unroll
      for (int mf = 0; mf < 2; ++mf) {
        int row = mf * 16 + lq;
        bf16x8 kf = *(const bf16x8*)(&lds[w * 8192 + row * 256
                                          + (((ks * 4 + grp) ^ (row & 7)) << 4)]);
#pragma unroll
        for (int qh = 0; qh < 2; ++qh)
          s[mf][qh] = __builtin_amdgcn_mfma_f32_16x16x32_bf16(kf, qf[ks][qh], s[mf][qh], 0, 0, 0);
      }

    asm volatile("s_waitcnt lgkmcnt(0)" ::: "memory");
    __builtin_amdgcn_sched_barrier(0);
    if (pre) stageK(kv0 + 256);

#pragma unroll
    for (int qh = 0; qh < 2; ++qh) {
      int tq = tq0 + qh * 16;
      bool hasmask = (kv0 + 31 > qt * 32 + qh * 16);
      if (hasmask) {
#pragma unroll
        for (int f = 0; f < 2; ++f)
#pragma unroll
          for (int r = 0; r < 4; ++r) {
            int kv = kv0 + f * 16 + grp * 4 + r;
            s[f][qh][r] = (kv <= tq) ? s[f][qh][r] : -__builtin_inff();
          }
      }
      float pmax = -__builtin_inff();
#pragma unroll
      for (int f = 0; f < 2; ++f)
#pragma unroll
        for (int r = 0; r < 4; ++r) pmax = fmaxf(pmax, s[f][qh][r]);
      pmax = fmaxf(pmax, __shfl_xor(pmax, 16, 64));
      pmax = fmaxf(pmax, __shfl_xor(pmax, 32, 64));

      float msub;
      if (__all(pmax <= mrun[qh])) {
        msub = mrun[qh];
      } else {
        float mnew = fmaxf(mrun[qh], pmax);
        msub = fmaxf(mnew, -3e38f);
        float corr = __expf(mrun[qh] - msub);
        lsum[qh] *= corr;
        mrun[qh] = mnew;
#pragma unroll
        for (int i2 = 0; i2 < 8; ++i2) accO[i2][qh] *= corr;
      }

      float psum = 0.f;
#pragma unroll
      for (int f = 0; f < 2; ++f) {
        bf16x4 pw;
#pragma unroll
        for (int r = 0; r < 4; ++r) {
          float pe = __expf(s[f][qh][r] - msub);
          psum += pe;
          pw[r] = (bf16_t)pe;
        }
        *(bf16x4*)(&lds[65536 + w * 2048 + qh * 1024 + ((f * 2 + (grp >> 1)) << 8)
                        + lq * 16 + ((grp & 1) << 3)]) = pw;
      }
      psum += __shfl_xor(psum, 16, 64);
      psum += __shfl_xor(psum, 32, 64);
      lsum[qh] += psum;
    }

    if (pre) { WAITVM(8); }
    else     { WAITVM(0); }
    __builtin_amdgcn_sched_barrier(0);

    bf16x8 pf0 = *(const bf16x8*)(&lds[65536 + w * 2048 + (grp << 8) + lq * 16]);
    bf16x8 pf1 = *(const bf16x8*)(&lds[65536 + w * 2048 + 1024 + (grp << 8) + lq * 16]);
#pragma unroll
    for (int mf = 0; mf < 8; ++mf) {
      accO[mf][0] = __builtin_amdgcn_mfma_f32_16x16x32_bf16(vf[mf], pf0, accO[mf][0], 0, 0, 0);
      accO[mf][1] = __builtin_amdgcn_mfma_f32_16x16x32_bf16(vf[mf], pf1, accO[mf][1], 0, 0, 0);
    }

    if (pre) loadV(kv0 + 256);
  }

  // ---- 8-way kv-split merge: 3-round LDS tree ----
#pragma unroll 1
  for (int round = 0; round < 3; ++round) {
    int stride = 4 >> round;
    __syncthreads();
    if (w >= stride && w < 2 * stride) {
      int slot = w - stride;
#pragma unroll
      for (int qh = 0; qh < 2; ++qh) {
#pragma unroll
        for (int mf = 0; mf < 8; ++mf)
          *(f32x4*)(&lds[slot * 16384 + qh * 8192 + mf * 1024 + lane * 16]) = accO[mf][qh];
        *(float*)(&lds[65536 + w * 2048 + qh * 512 + lane * 8])     = mrun[qh];
        *(float*)(&lds[65536 + w * 2048 + qh * 512 + lane * 8 + 4]) = lsum[qh];
      }
    }
    __syncthreads();
    if (w < stride) {
      int pw = w + stride;
#pragma unroll
      for (int qh = 0; qh < 2; ++qh) {
        float mB = *(const float*)(&lds[65536 + pw * 2048 + qh * 512 + lane * 8]);
        float lB = *(const float*)(&lds[65536 + pw * 2048 + qh * 512 + lane * 8 + 4]);
        float mN = fmaxf(mrun[qh], mB);
        float ms = fmaxf(mN, -3e38f);
        float cA = __expf(mrun[qh] - ms);
        float cB = __expf(mB - ms);
        lsum[qh] = lsum[qh] * cA + lB * cB;
        mrun[qh] = mN;
#pragma unroll
        for (int mf = 0; mf < 8; ++mf) {
          f32x4 OB = *(const f32x4*)(&lds[w * 16384 + qh * 8192 + mf * 1024 + lane * 16]);
#pragma unroll
          for (int e = 0; e < 4; ++e) accO[mf][qh][e] = accO[mf][qh][e] * cA + OB[e] * cB;
        }
      }
    }
  }

  if (w == 0) {
#pragma unroll
    for (int qh = 0; qh < 2; ++qh) {
      float inv = 1.0f / lsum[qh];
      float* orow = out + ((size_t)b * 2048 + tq0 + qh * 16) * 128;
#pragma unroll
      for (int mf = 0; mf < 8; ++mf) {
        f32x4 o;
#pragma unroll
        for (int e = 0; e < 4; ++e) o[e] = accO[mf][qh][e] * inv;
        *(f32x4*)(orow + mf * 16 + grp * 4) = o;
      }
    }
  }
}

extern "C" void kernel_launch(void* const* d_in, const int* in_sizes, int n_in,
                              void* d_out, int out_size, void* d_ws, size_t ws_size,
                              hipStream_t stream) {
  const float* x  = (const float*)d_in[0];
  const float* Wq = (const float*)d_in[1];
  const float* Wk = (const float*)d_in[2];
  const float* Wv = (const float*)d_in[3];
  float* out = (float*)d_out;
  char* ws = (char*)d_ws;

  bf16_t* wt = (bf16_t*)(ws + WT_OFF);
  bf16_t* qb = (bf16_t*)(ws + Q_OFF);
  bf16_t* kb = (bf16_t*)(ws + K_OFF);
  bf16_t* vT = (bf16_t*)(ws + VT_OFF);

  hipLaunchKernelGGL(wt_kernel, dim3(48), dim3(256), 0, stream, Wq, Wk, Wv, wt);
  hipLaunchKernelGGL(proj_kernel, dim3(1536), dim3(128), 0, stream, x, wt, qb, kb, vT);
  hipLaunchKernelGGL(attn_kernel, dim3(512), dim3(512), 0, stream, qb, kb, vT, out);
}